// Round 20
// baseline (404.162 us; speedup 1.0000x reference)
//
#include <hip/hip_runtime.h>
#include <stdint.h>

#define NB 8
#define NT 32
#define NN 1024
#define KSEL 16

typedef unsigned long long u64;
typedef unsigned int u32;

// total output element offsets (all float32)
#define O_IDX0 0ull
#define O_DIST 4194304ull
#define O_IDX1 8388608ull
#define O_PTS  12582912ull
#define O_PF   25165824ull
#define O_NORM 50331648ull
#define O_OUTX 62914560ull

#define F32_INF __uint_as_float(0x7F800000u)

#if __has_builtin(__builtin_amdgcn_fmed3f)
#define MED3(X, A, B) __builtin_amdgcn_fmed3f((X), (A), (B))
#else
#define MED3(X, A, B) __builtin_fminf(__builtin_fmaxf((X), (A)), (B))
#endif

__device__ __forceinline__ u32 fmap(float f) {
    u32 b = __float_as_uint(f);
    u32 m = (u32)((int)b >> 31) | 0x80000000u;
    return b ^ m;
}
// XLA-CPU reduce(sum(x*x)) with LLVM FMA contraction: fma(z,z, fma(x,x, y*y))
__device__ __forceinline__ float sq3(float x, float y, float z) {
    return __fmaf_rn(z, z, __fmaf_rn(x, x, __fmul_rn(y, y)));
}
// Eigen sgemm ascending-k FMA dot; d2 = (q2+p2) - 2*dot (2*dot exact)
__device__ __forceinline__ float d2f(float qx, float qy, float qz, float q2, float4 c) {
    float dot = __fmul_rn(qx, c.x);
    dot = __fmaf_rn(qy, c.y, dot);
    dot = __fmaf_rn(qz, c.z, dot);
    return __fsub_rn(__fadd_rn(q2, c.w), __fadd_rn(dot, dot));
}

// r9/r10-HW-verified exact stable insert; med3 K-update (r13..r19-verified).
#define INSERT16(D2V, JV)                                                        \
{                                                                                \
    _Pragma("unroll")                                                            \
    for (int s = KSEL - 1; s >= 1; --s) {                                        \
        ID[s] = ((D2V) < K[s - 1]) ? ID[s - 1] : (((D2V) < K[s]) ? (JV) : ID[s]);\
        K[s]  = MED3((D2V), K[s - 1], K[s]);                                     \
    }                                                                            \
    ID[0] = ((D2V) < K[0]) ? (JV) : ID[0];                                       \
    K[0]  = __builtin_fminf((D2V), K[0]);                                        \
}

// ---------------- Phase 1: nearest-neighbor chain (k=1), writes outx ----------------
// r19-HW-verified double-buffered version — kept verbatim.
__global__ __launch_bounds__(256) void chain_k(const float* __restrict__ P,
                                               float* __restrict__ outx) {
    __shared__ float4 sF[2][NN];
    const int tid = threadIdx.x;
    const int bid = blockIdx.x;
    const int b = bid >> 7;
    const int qb = (bid & 127) << 3;
    const int ln = tid & 63;
    const int q = qb + ((tid >> 6) << 1) + (ln >> 5);
    const int sl = ln & 31;
    const float* bp = P + (size_t)b * NT * NN * 3;

    float cx = bp[q * 3 + 0], cy = bp[q * 3 + 1], cz = bp[q * 3 + 2];

    // prologue: stage frame 0 into buffer 0
    {
        const float4* f4 = (const float4*)bp;
        float4 A = f4[tid * 3 + 0], Bv = f4[tid * 3 + 1], C = f4[tid * 3 + 2];
        sF[0][tid * 4 + 0] = make_float4(A.x, A.y, A.z, sq3(A.x, A.y, A.z));
        sF[0][tid * 4 + 1] = make_float4(A.w, Bv.x, Bv.y, sq3(A.w, Bv.x, Bv.y));
        sF[0][tid * 4 + 2] = make_float4(Bv.z, Bv.w, C.x, sq3(Bv.z, Bv.w, C.x));
        sF[0][tid * 4 + 3] = make_float4(C.y, C.z, C.w, sq3(C.y, C.z, C.w));
    }
    __syncthreads();

    int buf = 0;
    for (int t = 0; t < NT; ++t) {
        // issue next frame's global loads BEFORE compute (latency hides under it)
        float4 A2, B2, C2;
        if (t < NT - 1) {
            const float4* g4 = (const float4*)(bp + (size_t)(t + 1) * NN * 3);
            A2 = g4[tid * 3 + 0]; B2 = g4[tid * 3 + 1]; C2 = g4[tid * 3 + 2];
        }

        // ---- compute on sF[buf] (identical to verified chain) ----
        float q2 = sq3(cx, cy, cz);
        float bd = F32_INF;
        u32 bj = 0u;
        #pragma unroll 8
        for (int i = 0; i < 32; ++i) {
            int j = (i << 5) | sl;          // ascending per lane -> stable in-lane
            float d2 = d2f(cx, cy, cz, q2, sF[buf][j]);
            bool c_ = d2 < bd;
            bd = c_ ? d2 : bd;
            bj = c_ ? (u32)j : bj;
        }
        // cross-lane exact argmin with lowest-index tie-break via packed key
        u64 key = ((u64)fmap(bd) << 32) | (u64)bj;
        #pragma unroll
        for (int off = 1; off < 32; off <<= 1) {
            u64 o = __shfl_xor(key, off);
            key = (o < key) ? o : key;
        }
        int bi = (int)((u32)key & 1023u);
        float4 w = sF[buf][bi];
        cx = w.x; cy = w.y; cz = w.z;
        if (sl == 0) {
            float* o = outx + ((size_t)(b * NT + t) * NN + q) * 3;
            o[0] = cx; o[1] = cy; o[2] = cz;
        }

        // ---- stage t+1 into the opposite buffer (no conflict with reads of buf) ----
        if (t < NT - 1) {
            sF[buf ^ 1][tid * 4 + 0] = make_float4(A2.x, A2.y, A2.z, sq3(A2.x, A2.y, A2.z));
            sF[buf ^ 1][tid * 4 + 1] = make_float4(A2.w, B2.x, B2.y, sq3(A2.w, B2.x, B2.y));
            sF[buf ^ 1][tid * 4 + 2] = make_float4(B2.z, B2.w, C2.x, sq3(B2.z, B2.w, C2.x));
            sF[buf ^ 1][tid * 4 + 3] = make_float4(C2.y, C2.z, C2.w, sq3(C2.y, C2.z, C2.w));
        }
        __syncthreads();  // publishes t+1 staging; all waves done reading sF[buf]
        buf ^= 1;
    }
}

// ---------------- Phase 2: exact LDS filter + PIPELINED bitmask replay --------------
// r18/r19-HW-verified core. Single delta: chunk 0 fills only the first 16
// candidates directly; candidates 16..63 go through the same exact filter
// (thr = exact running K15 at j=16, a stale>=running threshold => superset)
// + the verified pipelined replay. Output bitwise-identical.
__global__ __launch_bounds__(256, 4) void topk_k(const float* __restrict__ P,
                                                 const float* __restrict__ outx,
                                                 float* __restrict__ out) {
    __shared__ float4 sC[NN];  // frame t   (x,y,z,|p|^2) 16KB
    __shared__ float4 sPv[NN]; // frame t-1 (x,y,z,0)     16KB
    const int tid = threadIdx.x;
    const int bid = blockIdx.x;
    const int b = bid >> 7;
    const int t = (bid >> 2) & 31;
    const int qc = bid & 3;
    const int q = (qc << 8) | tid;
    const float* bp = P + (size_t)b * NT * NN * 3;

    {
        const float4* f4 = (const float4*)(bp + (size_t)t * NN * 3);
        float4 A = f4[tid * 3 + 0], Bv = f4[tid * 3 + 1], C = f4[tid * 3 + 2];
        sC[tid * 4 + 0] = make_float4(A.x, A.y, A.z, sq3(A.x, A.y, A.z));
        sC[tid * 4 + 1] = make_float4(A.w, Bv.x, Bv.y, sq3(A.w, Bv.x, Bv.y));
        sC[tid * 4 + 2] = make_float4(Bv.z, Bv.w, C.x, sq3(Bv.z, Bv.w, C.x));
        sC[tid * 4 + 3] = make_float4(C.y, C.z, C.w, sq3(C.y, C.z, C.w));
        int tp = (t == 0) ? 0 : (t - 1);
        const float4* g4 = (const float4*)(bp + (size_t)tp * NN * 3);
        A = g4[tid * 3 + 0]; Bv = g4[tid * 3 + 1]; C = g4[tid * 3 + 2];
        sPv[tid * 4 + 0] = make_float4(A.x, A.y, A.z, 0.f);
        sPv[tid * 4 + 1] = make_float4(A.w, Bv.x, Bv.y, 0.f);
        sPv[tid * 4 + 2] = make_float4(Bv.z, Bv.w, C.x, 0.f);
        sPv[tid * 4 + 3] = make_float4(C.y, C.z, C.w, 0.f);
    }
    __syncthreads();

    // query point: x_cur(b,t,q)
    float cx, cy, cz;
    if (t == 0) {
        const float* qp = bp + (size_t)q * 3;
        cx = qp[0]; cy = qp[1]; cz = qp[2];
    } else {
        const float* qp = outx + ((size_t)(b * NT + (t - 1)) * NN + q) * 3;
        cx = qp[0]; cy = qp[1]; cz = qp[2];
    }
    // anchor = pts[b, t=0, q, k=0] = outx[b][0][q]
    const float* ap = outx + ((size_t)(b * NT) * NN + q) * 3;
    float ax = ap[0], ay = ap[1], az = ap[2];

    float q2 = sq3(cx, cy, cz);
    float K[KSEL];
    u32 ID[KSEL];
    #pragma unroll
    for (int i = 0; i < KSEL; i++) { K[i] = F32_INF; ID[i] = 0u; }

    // ---- candidates 0..15: direct exact fill (all enter; exact stable order) ----
    #pragma unroll 4
    for (u32 j = 0; j < 16; ++j) {
        float d2 = d2f(cx, cy, cz, q2, sC[j]);
        INSERT16(d2, j)
    }
    float thr = K[KSEL - 1];  // exact running K15 at j=16

    // ---- chunk 0 remainder (j=16..63): exact filter + pipelined replay ----
    {
        u32 mlo = 0u, mhi = 0u;
        #pragma unroll
        for (int jj = 16; jj < 32; ++jj) {
            float d2 = d2f(cx, cy, cz, q2, sC[jj]);
            mlo |= (d2 < thr) ? (1u << jj) : 0u;
        }
        #pragma unroll
        for (int jj = 32; jj < 64; ++jj) {
            float d2 = d2f(cx, cy, cz, q2, sC[jj]);
            mhi |= (d2 < thr) ? (1u << (jj - 32)) : 0u;
        }
        u64 msk = ((u64)mhi << 32) | (u64)mlo;
        int cm = __builtin_popcountll(msk);
        #pragma unroll
        for (int off = 1; off < 64; off <<= 1) {
            int o = __shfl_xor(cm, off);
            cm = (o > cm) ? o : cm;
        }
        cm = __builtin_amdgcn_readfirstlane(cm);

        bool act_c = msk != 0ull;
        u64 mm0 = act_c ? msk : 1ull;
        u32 j_cur = (u32)__builtin_ctzll(mm0);
        msk &= (msk - 1ull);
        float4 c_cur = sC[j_cur];

        for (int i = 0; i < cm; ++i) {
            bool act_n = msk != 0ull;
            u64 mmn = act_n ? msk : 1ull;
            u32 j_nxt = (u32)__builtin_ctzll(mmn);
            msk &= (msk - 1ull);
            float4 c_nxt = sC[j_nxt];

            float d2 = d2f(cx, cy, cz, q2, c_cur);
            float d2v = act_c ? d2 : F32_INF;
            INSERT16(d2v, j_cur)

            j_cur = j_nxt; c_cur = c_nxt; act_c = act_n;
        }
        thr = K[KSEL - 1];
    }

    // ---- chunks 1..15: exact LDS filter + pipelined bitmask exact replay ----
    for (int ch = 1; ch < 16; ++ch) {
        u32 mlo = 0u, mhi = 0u;
        #pragma unroll
        for (int jj = 0; jj < 64; ++jj) {
            float d2 = d2f(cx, cy, cz, q2, sC[(ch << 6) | jj]);
            bool h = d2 < thr;
            if (jj < 32) mlo |= h ? (1u << jj) : 0u;
            else         mhi |= h ? (1u << (jj - 32)) : 0u;
        }
        u64 msk = ((u64)mhi << 32) | (u64)mlo;
        int cm = __builtin_popcountll(msk);
        #pragma unroll
        for (int off = 1; off < 64; off <<= 1) {
            int o = __shfl_xor(cm, off);
            cm = (o > cm) ? o : cm;
        }
        cm = __builtin_amdgcn_readfirstlane(cm);

        // peel: extract first survivor + issue its load
        bool act_c = msk != 0ull;
        u64 mm0 = act_c ? msk : 1ull;
        u32 j_cur = ((u32)ch << 6) | (u32)__builtin_ctzll(mm0);
        msk &= (msk - 1ull);
        float4 c_cur = sC[j_cur];

        for (int i = 0; i < cm; ++i) {
            // extract NEXT survivor and issue its load before the current insert
            bool act_n = msk != 0ull;
            u64 mmn = act_n ? msk : 1ull;
            u32 j_nxt = ((u32)ch << 6) | (u32)__builtin_ctzll(mmn);
            msk &= (msk - 1ull);
            float4 c_nxt = sC[j_nxt];

            float d2 = d2f(cx, cy, cz, q2, c_cur);
            float d2v = act_c ? d2 : F32_INF;  // neutralize exhausted lanes
            INSERT16(d2v, j_cur)

            j_cur = j_nxt; c_cur = c_nxt; act_c = act_n;
        }
        thr = K[KSEL - 1];
    }

    size_t g = (size_t)(b * NT + t) * NN + q;

    // idxs (x2) and dist
    #pragma unroll
    for (int kk = 0; kk < KSEL; kk += 4) {
        float4 fi = make_float4((float)ID[kk + 0], (float)ID[kk + 1],
                                (float)ID[kk + 2], (float)ID[kk + 3]);
        float4 fd = make_float4(K[kk + 0], K[kk + 1], K[kk + 2], K[kk + 3]);
        *(float4*)(out + O_IDX0 + g * 16 + kk) = fi;
        *(float4*)(out + O_IDX1 + g * 16 + kk) = fi;
        *(float4*)(out + O_DIST + g * 16 + kk) = fd;
    }

    // pts, normalized, patchlet_feats
    #pragma unroll
    for (int kk = 0; kk < KSEL; kk += 4) {
        u32 i0 = ID[kk + 0], i1 = ID[kk + 1], i2 = ID[kk + 2], i3 = ID[kk + 3];
        float4 p0 = sC[i0], p1 = sC[i1], p2v = sC[i2], p3 = sC[i3];
        float4 f0 = sPv[i0], f1 = sPv[i1], f2v = sPv[i2], f3 = sPv[i3];
        float n0x = p0.x - ax, n0y = p0.y - ay, n0z = p0.z - az;
        float n1x = p1.x - ax, n1y = p1.y - ay, n1z = p1.z - az;
        float n2x = p2v.x - ax, n2y = p2v.y - ay, n2z = p2v.z - az;
        float n3x = p3.x - ax, n3y = p3.y - ay, n3z = p3.z - az;

        float* pp = out + O_PTS + g * 48 + kk * 3;
        ((float4*)pp)[0] = make_float4(p0.x, p0.y, p0.z, p1.x);
        ((float4*)pp)[1] = make_float4(p1.y, p1.z, p2v.x, p2v.y);
        ((float4*)pp)[2] = make_float4(p2v.z, p3.x, p3.y, p3.z);

        float* np = out + O_NORM + g * 48 + kk * 3;
        ((float4*)np)[0] = make_float4(n0x, n0y, n0z, n1x);
        ((float4*)np)[1] = make_float4(n1y, n1z, n2x, n2y);
        ((float4*)np)[2] = make_float4(n2z, n3x, n3y, n3z);

        float* fp = out + O_PF + g * 96 + kk * 6;
        ((float4*)fp)[0] = make_float4(f0.x, f0.y, f0.z, n0x);
        ((float4*)fp)[1] = make_float4(n0y, n0z, f1.x, f1.y);
        ((float4*)fp)[2] = make_float4(f1.z, n1x, n1y, n1z);
        ((float4*)fp)[3] = make_float4(f2v.x, f2v.y, f2v.z, n2x);
        ((float4*)fp)[4] = make_float4(n2y, n2z, f3.x, f3.y);
        ((float4*)fp)[5] = make_float4(f3.z, n3x, n3y, n3z);
    }
}

extern "C" void kernel_launch(void* const* d_in, const int* in_sizes, int n_in,
                              void* d_out, int out_size, void* d_ws, size_t ws_size,
                              hipStream_t stream) {
    const float* P = (const float*)d_in[0];
    float* out = (float*)d_out;
    float* outx = out + O_OUTX;
    chain_k<<<dim3(1024), dim3(256), 0, stream>>>(P, outx);
    topk_k<<<dim3(1024), dim3(256), 0, stream>>>(P, outx, out);
}

// Round 21
// 364.750 us; speedup vs baseline: 1.1081x; 1.1081x over previous
//
#include <hip/hip_runtime.h>
#include <stdint.h>

#define NB 8
#define NT 32
#define NN 1024
#define KSEL 16

typedef unsigned long long u64;
typedef unsigned int u32;

// total output element offsets (all float32)
#define O_IDX0 0ull
#define O_DIST 4194304ull
#define O_IDX1 8388608ull
#define O_PTS  12582912ull
#define O_PF   25165824ull
#define O_NORM 50331648ull
#define O_OUTX 62914560ull

#define F32_INF __uint_as_float(0x7F800000u)

#if __has_builtin(__builtin_amdgcn_fmed3f)
#define MED3(X, A, B) __builtin_amdgcn_fmed3f((X), (A), (B))
#else
#define MED3(X, A, B) __builtin_fminf(__builtin_fmaxf((X), (A)), (B))
#endif

__device__ __forceinline__ u32 fmap(float f) {
    u32 b = __float_as_uint(f);
    u32 m = (u32)((int)b >> 31) | 0x80000000u;
    return b ^ m;
}
// XLA-CPU reduce(sum(x*x)) with LLVM FMA contraction: fma(z,z, fma(x,x, y*y))
__device__ __forceinline__ float sq3(float x, float y, float z) {
    return __fmaf_rn(z, z, __fmaf_rn(x, x, __fmul_rn(y, y)));
}
// Eigen sgemm ascending-k FMA dot; d2 = (q2+p2) - 2*dot (2*dot exact)
__device__ __forceinline__ float d2f(float qx, float qy, float qz, float q2, float4 c) {
    float dot = __fmul_rn(qx, c.x);
    dot = __fmaf_rn(qy, c.y, dot);
    dot = __fmaf_rn(qz, c.z, dot);
    return __fsub_rn(__fadd_rn(q2, c.w), __fadd_rn(dot, dot));
}

// r9/r10-HW-verified exact stable insert; med3 K-update (r13..r19-verified).
#define INSERT16(D2V, JV)                                                        \
{                                                                                \
    _Pragma("unroll")                                                            \
    for (int s = KSEL - 1; s >= 1; --s) {                                        \
        ID[s] = ((D2V) < K[s - 1]) ? ID[s - 1] : (((D2V) < K[s]) ? (JV) : ID[s]);\
        K[s]  = MED3((D2V), K[s - 1], K[s]);                                     \
    }                                                                            \
    ID[0] = ((D2V) < K[0]) ? (JV) : ID[0];                                       \
    K[0]  = __builtin_fminf((D2V), K[0]);                                        \
}

// ---------------- Phase 1: nearest-neighbor chain (k=1), writes outx ----------------
// r19-HW-verified double-buffered version.
__global__ __launch_bounds__(256) void chain_k(const float* __restrict__ P,
                                               float* __restrict__ outx) {
    __shared__ float4 sF[2][NN];
    const int tid = threadIdx.x;
    const int bid = blockIdx.x;
    const int b = bid >> 7;
    const int qb = (bid & 127) << 3;
    const int ln = tid & 63;
    const int q = qb + ((tid >> 6) << 1) + (ln >> 5);
    const int sl = ln & 31;
    const float* bp = P + (size_t)b * NT * NN * 3;

    float cx = bp[q * 3 + 0], cy = bp[q * 3 + 1], cz = bp[q * 3 + 2];

    // prologue: stage frame 0 into buffer 0
    {
        const float4* f4 = (const float4*)bp;
        float4 A = f4[tid * 3 + 0], Bv = f4[tid * 3 + 1], C = f4[tid * 3 + 2];
        sF[0][tid * 4 + 0] = make_float4(A.x, A.y, A.z, sq3(A.x, A.y, A.z));
        sF[0][tid * 4 + 1] = make_float4(A.w, Bv.x, Bv.y, sq3(A.w, Bv.x, Bv.y));
        sF[0][tid * 4 + 2] = make_float4(Bv.z, Bv.w, C.x, sq3(Bv.z, Bv.w, C.x));
        sF[0][tid * 4 + 3] = make_float4(C.y, C.z, C.w, sq3(C.y, C.z, C.w));
    }
    __syncthreads();

    int buf = 0;
    for (int t = 0; t < NT; ++t) {
        // issue next frame's global loads BEFORE compute (latency hides under it)
        float4 A2, B2, C2;
        if (t < NT - 1) {
            const float4* g4 = (const float4*)(bp + (size_t)(t + 1) * NN * 3);
            A2 = g4[tid * 3 + 0]; B2 = g4[tid * 3 + 1]; C2 = g4[tid * 3 + 2];
        }

        // ---- compute on sF[buf] (identical to verified chain) ----
        float q2 = sq3(cx, cy, cz);
        float bd = F32_INF;
        u32 bj = 0u;
        #pragma unroll 8
        for (int i = 0; i < 32; ++i) {
            int j = (i << 5) | sl;          // ascending per lane -> stable in-lane
            float d2 = d2f(cx, cy, cz, q2, sF[buf][j]);
            bool c_ = d2 < bd;
            bd = c_ ? d2 : bd;
            bj = c_ ? (u32)j : bj;
        }
        // cross-lane exact argmin with lowest-index tie-break via packed key
        u64 key = ((u64)fmap(bd) << 32) | (u64)bj;
        #pragma unroll
        for (int off = 1; off < 32; off <<= 1) {
            u64 o = __shfl_xor(key, off);
            key = (o < key) ? o : key;
        }
        int bi = (int)((u32)key & 1023u);
        float4 w = sF[buf][bi];
        cx = w.x; cy = w.y; cz = w.z;
        if (sl == 0) {
            float* o = outx + ((size_t)(b * NT + t) * NN + q) * 3;
            o[0] = cx; o[1] = cy; o[2] = cz;
        }

        // ---- stage t+1 into the opposite buffer (no conflict with reads of buf) ----
        if (t < NT - 1) {
            sF[buf ^ 1][tid * 4 + 0] = make_float4(A2.x, A2.y, A2.z, sq3(A2.x, A2.y, A2.z));
            sF[buf ^ 1][tid * 4 + 1] = make_float4(A2.w, B2.x, B2.y, sq3(A2.w, B2.x, B2.y));
            sF[buf ^ 1][tid * 4 + 2] = make_float4(B2.z, B2.w, C2.x, sq3(B2.z, B2.w, C2.x));
            sF[buf ^ 1][tid * 4 + 3] = make_float4(C2.y, C2.z, C2.w, sq3(C2.y, C2.z, C2.w));
        }
        __syncthreads();  // publishes t+1 staging; all waves done reading sF[buf]
        buf ^= 1;
    }
}

// ---------------- Phase 2: exact LDS filter + PIPELINED bitmask replay --------------
// r18/r19-HW-verified (best measured) — kept verbatim. Chunk 0 is a direct
// fill (r20 showed a 16-seen threshold passes ~94% of candidates — filtering
// chunk 0 is strictly worse).
__global__ __launch_bounds__(256, 4) void topk_k(const float* __restrict__ P,
                                                 const float* __restrict__ outx,
                                                 float* __restrict__ out) {
    __shared__ float4 sC[NN];  // frame t   (x,y,z,|p|^2) 16KB
    __shared__ float4 sPv[NN]; // frame t-1 (x,y,z,0)     16KB
    const int tid = threadIdx.x;
    const int bid = blockIdx.x;
    const int b = bid >> 7;
    const int t = (bid >> 2) & 31;
    const int qc = bid & 3;
    const int q = (qc << 8) | tid;
    const float* bp = P + (size_t)b * NT * NN * 3;

    {
        const float4* f4 = (const float4*)(bp + (size_t)t * NN * 3);
        float4 A = f4[tid * 3 + 0], Bv = f4[tid * 3 + 1], C = f4[tid * 3 + 2];
        sC[tid * 4 + 0] = make_float4(A.x, A.y, A.z, sq3(A.x, A.y, A.z));
        sC[tid * 4 + 1] = make_float4(A.w, Bv.x, Bv.y, sq3(A.w, Bv.x, Bv.y));
        sC[tid * 4 + 2] = make_float4(Bv.z, Bv.w, C.x, sq3(Bv.z, Bv.w, C.x));
        sC[tid * 4 + 3] = make_float4(C.y, C.z, C.w, sq3(C.y, C.z, C.w));
        int tp = (t == 0) ? 0 : (t - 1);
        const float4* g4 = (const float4*)(bp + (size_t)tp * NN * 3);
        A = g4[tid * 3 + 0]; Bv = g4[tid * 3 + 1]; C = g4[tid * 3 + 2];
        sPv[tid * 4 + 0] = make_float4(A.x, A.y, A.z, 0.f);
        sPv[tid * 4 + 1] = make_float4(A.w, Bv.x, Bv.y, 0.f);
        sPv[tid * 4 + 2] = make_float4(Bv.z, Bv.w, C.x, 0.f);
        sPv[tid * 4 + 3] = make_float4(C.y, C.z, C.w, 0.f);
    }
    __syncthreads();

    // query point: x_cur(b,t,q)
    float cx, cy, cz;
    if (t == 0) {
        const float* qp = bp + (size_t)q * 3;
        cx = qp[0]; cy = qp[1]; cz = qp[2];
    } else {
        const float* qp = outx + ((size_t)(b * NT + (t - 1)) * NN + q) * 3;
        cx = qp[0]; cy = qp[1]; cz = qp[2];
    }
    // anchor = pts[b, t=0, q, k=0] = outx[b][0][q]
    const float* ap = outx + ((size_t)(b * NT) * NN + q) * 3;
    float ax = ap[0], ay = ap[1], az = ap[2];

    float q2 = sq3(cx, cy, cz);
    float K[KSEL];
    u32 ID[KSEL];
    #pragma unroll
    for (int i = 0; i < KSEL; i++) { K[i] = F32_INF; ID[i] = 0u; }

    // ---- chunk 0: direct exact fill, pipelined 1-ahead ----
    {
        float4 c_cur = sC[0];
        #pragma unroll 4
        for (int j = 0; j < 64; ++j) {
            float4 c_nxt = sC[(j < 63) ? (j + 1) : 63];  // prefetch before insert
            float d2 = d2f(cx, cy, cz, q2, c_cur);
            INSERT16(d2, (u32)j)
            c_cur = c_nxt;
        }
    }
    float thr = K[KSEL - 1];

    // ---- chunks 1..15: exact LDS filter + pipelined bitmask exact replay ----
    for (int ch = 1; ch < 16; ++ch) {
        u32 mlo = 0u, mhi = 0u;
        #pragma unroll
        for (int jj = 0; jj < 64; ++jj) {
            float d2 = d2f(cx, cy, cz, q2, sC[(ch << 6) | jj]);
            bool h = d2 < thr;
            if (jj < 32) mlo |= h ? (1u << jj) : 0u;
            else         mhi |= h ? (1u << (jj - 32)) : 0u;
        }
        u64 msk = ((u64)mhi << 32) | (u64)mlo;
        int cm = __builtin_popcountll(msk);
        #pragma unroll
        for (int off = 1; off < 64; off <<= 1) {
            int o = __shfl_xor(cm, off);
            cm = (o > cm) ? o : cm;
        }
        cm = __builtin_amdgcn_readfirstlane(cm);

        // peel: extract first survivor + issue its load
        bool act_c = msk != 0ull;
        u64 mm0 = act_c ? msk : 1ull;
        u32 j_cur = ((u32)ch << 6) | (u32)__builtin_ctzll(mm0);
        msk &= (msk - 1ull);
        float4 c_cur = sC[j_cur];

        for (int i = 0; i < cm; ++i) {
            // extract NEXT survivor and issue its load before the current insert
            bool act_n = msk != 0ull;
            u64 mmn = act_n ? msk : 1ull;
            u32 j_nxt = ((u32)ch << 6) | (u32)__builtin_ctzll(mmn);
            msk &= (msk - 1ull);
            float4 c_nxt = sC[j_nxt];

            float d2 = d2f(cx, cy, cz, q2, c_cur);
            float d2v = act_c ? d2 : F32_INF;  // neutralize exhausted lanes
            INSERT16(d2v, j_cur)

            j_cur = j_nxt; c_cur = c_nxt; act_c = act_n;
        }
        thr = K[KSEL - 1];
    }

    size_t g = (size_t)(b * NT + t) * NN + q;

    // idxs (x2) and dist
    #pragma unroll
    for (int kk = 0; kk < KSEL; kk += 4) {
        float4 fi = make_float4((float)ID[kk + 0], (float)ID[kk + 1],
                                (float)ID[kk + 2], (float)ID[kk + 3]);
        float4 fd = make_float4(K[kk + 0], K[kk + 1], K[kk + 2], K[kk + 3]);
        *(float4*)(out + O_IDX0 + g * 16 + kk) = fi;
        *(float4*)(out + O_IDX1 + g * 16 + kk) = fi;
        *(float4*)(out + O_DIST + g * 16 + kk) = fd;
    }

    // pts, normalized, patchlet_feats
    #pragma unroll
    for (int kk = 0; kk < KSEL; kk += 4) {
        u32 i0 = ID[kk + 0], i1 = ID[kk + 1], i2 = ID[kk + 2], i3 = ID[kk + 3];
        float4 p0 = sC[i0], p1 = sC[i1], p2v = sC[i2], p3 = sC[i3];
        float4 f0 = sPv[i0], f1 = sPv[i1], f2v = sPv[i2], f3 = sPv[i3];
        float n0x = p0.x - ax, n0y = p0.y - ay, n0z = p0.z - az;
        float n1x = p1.x - ax, n1y = p1.y - ay, n1z = p1.z - az;
        float n2x = p2v.x - ax, n2y = p2v.y - ay, n2z = p2v.z - az;
        float n3x = p3.x - ax, n3y = p3.y - ay, n3z = p3.z - az;

        float* pp = out + O_PTS + g * 48 + kk * 3;
        ((float4*)pp)[0] = make_float4(p0.x, p0.y, p0.z, p1.x);
        ((float4*)pp)[1] = make_float4(p1.y, p1.z, p2v.x, p2v.y);
        ((float4*)pp)[2] = make_float4(p2v.z, p3.x, p3.y, p3.z);

        float* np = out + O_NORM + g * 48 + kk * 3;
        ((float4*)np)[0] = make_float4(n0x, n0y, n0z, n1x);
        ((float4*)np)[1] = make_float4(n1y, n1z, n2x, n2y);
        ((float4*)np)[2] = make_float4(n2z, n3x, n3y, n3z);

        float* fp = out + O_PF + g * 96 + kk * 6;
        ((float4*)fp)[0] = make_float4(f0.x, f0.y, f0.z, n0x);
        ((float4*)fp)[1] = make_float4(n0y, n0z, f1.x, f1.y);
        ((float4*)fp)[2] = make_float4(f1.z, n1x, n1y, n1z);
        ((float4*)fp)[3] = make_float4(f2v.x, f2v.y, f2v.z, n2x);
        ((float4*)fp)[4] = make_float4(n2y, n2z, f3.x, f3.y);
        ((float4*)fp)[5] = make_float4(f3.z, n3x, n3y, n3z);
    }
}

extern "C" void kernel_launch(void* const* d_in, const int* in_sizes, int n_in,
                              void* d_out, int out_size, void* d_ws, size_t ws_size,
                              hipStream_t stream) {
    const float* P = (const float*)d_in[0];
    float* out = (float*)d_out;
    float* outx = out + O_OUTX;
    chain_k<<<dim3(1024), dim3(256), 0, stream>>>(P, outx);
    topk_k<<<dim3(1024), dim3(256), 0, stream>>>(P, outx, out);
}